// Round 5
// baseline (427.884 us; speedup 1.0000x reference)
//
#include <hip/hip_runtime.h>
#include <hip/hip_cooperative_groups.h>
#include <math.h>

namespace cg = cooperative_groups;

// TOF PET forward projection.
// History: R3 97us proj (L2 thrash) -> R4 Morton sort FETCH 215->26MB ->
// R6 4 lanes/LOR: proj 67 -> R7 sorted records + 8 lanes: proj 50 -> R8
// exact-fast-path voxel divide: 44.5 (VALU 74->54) -> R9 unroll: NEUTRAL ->
// R10 affine index: NEUTRAL -> R11 2x2x4 brick gather: proj ~42-44.
// R12 finding: harness re-poison fill (256MiB, 44us @76% HBM peak) is a
// fixed floor; proj ~43; the remaining ~50us is 5 setup dispatches + gaps.
// R12: fuse memset-adjacent setup into ONE cooperative kernel:
//   P1 bucket (key + EXACT ray record, kept in registers across grid.sync)
//   P2 scan: blocks 0..127 hierarchical scan | blocks >=128 brickify
//   P3 scatter from registers.
// 5 dispatches -> 2; scan parallelized; brickify hidden under scan.
// All numeric paths verbatim from R11 => records bit-identical; only
// within-bucket slot order changes (summation-order free, validated R4-R6).
// Index-path math STRICTLY UNFUSED exact-rn f32 — DO NOT approximate or
// contract (R0-R2: voxel flips => absmax 0.14 > 0.071). Affine guard bound
// proven R10 (fallback to exact chain within 1e-3 of integer boundary).

#define NB_POS 4096          // 16^3 Morton cells, 25 mm
#define NCLS   8             // window-length classes (16-sample bins)
#define NBUCK  (NB_POS * NCLS)
#define NSB    (NBUCK / 256) // scan blocks = 128
#define SPL    8             // lanes per LOR

__device__ __forceinline__ int morton4(int x, int y, int z) {
    int m = 0;
#pragma unroll
    for (int b = 0; b < 4; ++b) {
        m |= ((x >> b) & 1) << (3 * b + 0);
        m |= ((y >> b) & 1) << (3 * b + 1);
        m |= ((z >> b) & 1) << (3 * b + 2);
    }
    return m;
}

// Fallback-kernel voxel index: bit-identical to (int)floorf(xs/3.125f).
__device__ __forceinline__ int vox_of(float xs) {
#pragma clang fp contract(off)
    float q  = xs * 0.32f;
    float fq = floorf(q);
    float f  = q - fq;                      // exact (Sterbenz-range)
    if (__builtin_expect(f < 1e-4f || f > 0.9999f, 0)) {
        fq = floorf(xs / 3.125f);           // exact rn div — rare path
    }
    return min(max((int)fq, 0), 127);
}

// Slab clip (strictly unfused, exact rn divs — reference-visible tmin/span).
__device__ __forceinline__ void slab_clip(
    float p1x, float p1y, float p1z, float dx, float dy, float dz,
    float& tmin, float& tmax)
{
    const float eps = 1e-8f;
    float sdx = (fabsf(dx) < eps) ? eps : dx;
    float sdy = (fabsf(dy) < eps) ? eps : dy;
    float sdz = (fabsf(dz) < eps) ? eps : dz;
    float tax = (-200.f - p1x) / sdx, tbx = (200.f - p1x) / sdx;
    float tay = (-200.f - p1y) / sdy, tby = (200.f - p1y) / sdy;
    float taz = (-200.f - p1z) / sdz, tbz = (200.f - p1z) / sdz;
    tmin = fmaxf(fmaxf(fmaxf(fminf(tax, tbx), fminf(tay, tby)),
                       fminf(taz, tbz)), 0.f);
    tmax = fminf(fminf(fminf(fmaxf(tax, tbx), fmaxf(tay, tby)),
                       fmaxf(taz, tbz)), 1.f);
}

// ---------------- fused cooperative setup ----------------
__global__ __launch_bounds__(256) void setup_kernel(
    const float* __restrict__ lors, const float* __restrict__ image,
    int* __restrict__ counts, int* __restrict__ offsets,
    int* __restrict__ bsum, int* __restrict__ bpre,
    float4* __restrict__ recS, float4* __restrict__ ls8,
    float* __restrict__ bimg, int n)
{
#pragma clang fp contract(off)
    cg::grid_group grid = cg::this_grid();
    const int tid = (int)threadIdx.x;
    const int bid = (int)blockIdx.x;
    const int i = bid * 256 + tid;

    // ---- P1: bucket + EXACT ray record (registers persist to P3) ----
    float p1x = 0, p1y = 0, p1z = 0, p2x = 0, p2y = 0, p2z = 0, tt = 0;
    float tmin = 0, span = 0, recL = 0;
    int jlo = 0, jhi = -1;
    unsigned key = 0;
    const bool havel = (i < n);
    if (havel) {
        const float* lp = lors + (size_t)i * 7;
        p1x = lp[0]; p1y = lp[1]; p1z = lp[2];
        p2x = lp[3]; p2y = lp[4]; p2z = lp[5];
        tt  = lp[6];
        const float dx = p2x - p1x, dy = p2y - p1y, dz = p2z - p1z;
        const float L = sqrtf(((dx * dx) + (dy * dy)) + (dz * dz));
        float tmax;
        slab_clip(p1x, p1y, p1z, dx, dy, dz, tmin, tmax);
        if (!(tmax > tmin) || !(L > 0.f)) {
            key = (unsigned)i & (NBUCK - 1);       // spread invalids
            tmin = 0.f; span = 0.f; recL = 0.f; jlo = 0; jhi = -1;
        } else {
            span = tmax - tmin; recL = L;
            // sort key (approx math OK — key only)
            float tc = fminf(fmaxf(0.5f + tt / L, tmin), tmax);
            float px = p1x + tc * dx, py = p1y + tc * dy, pz = p1z + tc * dz;
            int cx = (int)fminf(fmaxf((px + 200.f) * 0.04f, 0.f), 15.f);
            int cy = (int)fminf(fmaxf((py + 200.f) * 0.04f, 0.f), 15.f);
            int cz = (int)fminf(fmaxf((pz + 200.f) * 0.04f, 0.f), 15.f);
            float jla = ((0.5f + (tt - 90.f) / L) - tmin) / span * 128.f;
            float jha = ((0.5f + (tt + 90.f) / L) - tmin) / span * 128.f;
            jla = fmaxf(jla, 0.f); jha = fminf(jha, 128.f);
            float wlen = fmaxf(jha - jla, 0.f);
            int cls = min(NCLS - 1, (int)(wlen * (1.f / 16.f)));
            key = ((unsigned)morton4(cx, cy, cz) << 3) | (unsigned)cls;
            // EXACT sample range (verbatim R11 scatter math, unfused)
            const float tlo = 0.5f + (tt - 90.0f) / L;
            const float thi = 0.5f + (tt + 90.0f) / L;
            float jl = ((tlo - tmin) / span) * 128.0f - 0.5f;
            float jh = ((thi - tmin) / span) * 128.0f - 0.5f;
            jl = fminf(fmaxf(jl - 2.0f, 0.0f), 127.0f);
            jh = fminf(fmaxf(jh + 2.0f, -1.0f), 127.0f);
            jlo = (int)jl;
            jhi = (int)ceilf(jh);
            if (jhi > 127) jhi = 127;
        }
        atomicAdd(&counts[key], 1);
    }
    grid.sync();                                   // S1: counts done

    // ---- P2A: blocks<NSB scan 256 buckets each | others brickify ----
    __shared__ int sd[256];
    int myc = 0, incl = 0;
    if (bid < NSB) {
        const int g = bid * 256 + tid;
        myc = counts[g];
        sd[tid] = myc; __syncthreads();
        for (int off = 1; off < 256; off <<= 1) {
            int v = (tid >= off) ? sd[tid - off] : 0;
            __syncthreads();
            sd[tid] += v;
            __syncthreads();
        }
        incl = sd[tid];
        if (tid == 255) bsum[bid] = incl;
    } else {
        // brickify 128^3 image into 2x2x4 bricks (one 64B line each)
        const int stride = ((int)gridDim.x - NSB) * 256;
        for (int o = (bid - NSB) * 256 + tid; o < 128 * 128 * 128;
             o += stride) {
            const int off_ = o & 15;
            const int brick = o >> 4;
            const int bz = brick & 31;
            const int t2 = brick >> 5;
            const int by = t2 & 63;
            const int bx = t2 >> 6;
            const int oz = off_ & 3, oy = (off_ >> 2) & 1, ox = off_ >> 3;
            const int vx = (bx << 1) | ox, vy = (by << 1) | oy,
                      vz = (bz << 2) | oz;
            bimg[o] = image[(((vx << 7) | vy) << 7) | vz];
        }
    }
    grid.sync();                                   // S2: bsum done

    // ---- P2B: block 0 scans the 128 block sums ----
    if (bid == 0) {
        const int b0 = (tid < NSB) ? bsum[tid] : 0;
        sd[tid] = b0; __syncthreads();
        for (int off = 1; off < 256; off <<= 1) {
            int v = (tid >= off) ? sd[tid - off] : 0;
            __syncthreads();
            sd[tid] += v;
            __syncthreads();
        }
        if (tid < NSB) bpre[tid] = sd[tid] - b0;   // exclusive
    }
    grid.sync();                                   // S3: bpre done

    // ---- P2C: write final exclusive offsets ----
    if (bid < NSB) {
        const int g = bid * 256 + tid;
        offsets[g] = bpre[bid] + (incl - myc);
    }
    grid.sync();                                   // S4: offsets done

    // ---- P3: scatter from registers ----
    if (havel) {
        const int slot = atomicAdd(&offsets[key], 1);
        const int pk = (jlo << 16) | (jhi & 0xFFFF);
        recS[slot] = make_float4(tmin, span, recL, __int_as_float(pk));
        ls8[2 * slot + 0] = make_float4(p1x, p1y, p1z, p2x);
        ls8[2 * slot + 1] = make_float4(p2y, p2z, tt, __int_as_float(i));
    }
}

// ---------------- fallback (non-cooperative) setup path ----------------
__global__ void bucket_kernel(const float* __restrict__ lors,
                              int* __restrict__ counts,
                              int* __restrict__ tmp, int n) {
#pragma clang fp contract(off)
    int i = blockIdx.x * 256 + threadIdx.x;
    if (i >= n) return;
    const float* lp = lors + (size_t)i * 7;
    float p1x = lp[0], p1y = lp[1], p1z = lp[2];
    float dx = lp[3] - p1x, dy = lp[4] - p1y, dz = lp[5] - p1z;
    float tt = lp[6];
    float L = sqrtf(((dx * dx) + (dy * dy)) + (dz * dz));
    float tmin, tmax;
    slab_clip(p1x, p1y, p1z, dx, dy, dz, tmin, tmax);
    unsigned key;
    if (!(tmax > tmin) || !(L > 0.f)) {
        key = (unsigned)i & (NBUCK - 1);
    } else {
        float span = tmax - tmin;
        float tc = fminf(fmaxf(0.5f + tt / L, tmin), tmax);
        float px = p1x + tc * dx, py = p1y + tc * dy, pz = p1z + tc * dz;
        int cx = (int)fminf(fmaxf((px + 200.f) * 0.04f, 0.f), 15.f);
        int cy = (int)fminf(fmaxf((py + 200.f) * 0.04f, 0.f), 15.f);
        int cz = (int)fminf(fmaxf((pz + 200.f) * 0.04f, 0.f), 15.f);
        float jl = ((0.5f + (tt - 90.f) / L) - tmin) / span * 128.f;
        float jh = ((0.5f + (tt + 90.f) / L) - tmin) / span * 128.f;
        jl = fmaxf(jl, 0.f); jh = fminf(jh, 128.f);
        float wlen = fmaxf(jh - jl, 0.f);
        int cls = min(NCLS - 1, (int)(wlen * (1.f / 16.f)));
        key = ((unsigned)morton4(cx, cy, cz) << 3) | (unsigned)cls;
    }
    atomicAdd(&counts[key], 1);
    tmp[i] = (int)key;
}

__global__ void scan_kernel(const int* __restrict__ counts,
                            int* __restrict__ offsets) {
    __shared__ int s[1024];
    int t = threadIdx.x;
    const int PER = NBUCK / 1024;
    int base = t * PER;
    int local[PER];
    int sum = 0;
#pragma unroll
    for (int i = 0; i < PER; ++i) { local[i] = counts[base + i]; sum += local[i]; }
    s[t] = sum;
    __syncthreads();
    for (int off = 1; off < 1024; off <<= 1) {
        int v = (t >= off) ? s[t - off] : 0;
        __syncthreads();
        s[t] += v;
        __syncthreads();
    }
    int excl = (t == 0) ? 0 : s[t - 1];
#pragma unroll
    for (int i = 0; i < PER; ++i) { offsets[base + i] = excl; excl += local[i]; }
}

__global__ void scatter_kernel(const float* __restrict__ lors,
                               const int* __restrict__ tmp,
                               int* __restrict__ offsets,
                               float4* __restrict__ recS,
                               float4* __restrict__ ls8,
                               int n) {
#pragma clang fp contract(off)
    int i = blockIdx.x * 256 + threadIdx.x;
    if (i >= n) return;
    const float* lp = lors + (size_t)i * 7;
    float p1x = lp[0], p1y = lp[1], p1z = lp[2];
    float p2x = lp[3], p2y = lp[4], p2z = lp[5];
    float tt = lp[6];
    float dx = p2x - p1x, dy = p2y - p1y, dz = p2z - p1z;
    float L = sqrtf(((dx * dx) + (dy * dy)) + (dz * dz));
    float tmin, tmax;
    slab_clip(p1x, p1y, p1z, dx, dy, dz, tmin, tmax);
    float span, recL;
    int jlo, jhi;
    if (!(tmax > tmin) || !(L > 0.f)) {
        tmin = 0.f; span = 0.f; recL = 0.f; jlo = 0; jhi = -1;
    } else {
        span = tmax - tmin;
        recL = L;
        const float tlo = 0.5f + (tt - 90.0f) / L;
        const float thi = 0.5f + (tt + 90.0f) / L;
        float jl = ((tlo - tmin) / span) * 128.0f - 0.5f;
        float jh = ((thi - tmin) / span) * 128.0f - 0.5f;
        jl = fminf(fmaxf(jl - 2.0f, 0.0f), 127.0f);
        jh = fminf(fmaxf(jh + 2.0f, -1.0f), 127.0f);
        jlo = (int)jl;
        jhi = (int)ceilf(jh);
        if (jhi > 127) jhi = 127;
    }
    int slot = atomicAdd(&offsets[tmp[i]], 1);
    int pk = (jlo << 16) | (jhi & 0xFFFF);
    recS[slot] = make_float4(tmin, span, recL, __int_as_float(pk));
    ls8[2 * slot + 0] = make_float4(p1x, p1y, p1z, p2x);
    ls8[2 * slot + 1] = make_float4(p2y, p2z, tt, __int_as_float(i));
}

__global__ __launch_bounds__(256) void brickify_kernel(
    const float* __restrict__ image, float* __restrict__ bimg) {
    const int o = blockIdx.x * 256 + threadIdx.x;
    const int off = o & 15;
    const int brick = o >> 4;
    const int bz = brick & 31;
    const int t  = brick >> 5;
    const int by = t & 63;
    const int bx = t >> 6;
    const int oz = off & 3, oy = (off >> 2) & 1, ox = off >> 3;
    const int vx = (bx << 1) | ox, vy = (by << 1) | oy, vz = (bz << 2) | oz;
    bimg[o] = image[(((vx << 7) | vy) << 7) | vz];
}

// ---------------- projection ----------------
template <bool BRICK>
__global__ __launch_bounds__(256) void proj_kernel(
    const float* __restrict__ img,     // bricked if BRICK, else linear
    const float4* __restrict__ recS,
    const float4* __restrict__ ls8,
    float* __restrict__ out,
    int n_lors, int chunks)
{
#pragma clang fp contract(off)
    const int b = blockIdx.x;
    const int sb = (b & 7) * chunks + (b >> 3);    // XCD swizzle
    const int idx = sb * 256 + (int)threadIdx.x;
    const int gid = idx >> 3;          // sorted LOR slot
    const int s   = idx & 7;           // sub-lane 0..7
    if (gid >= n_lors) return;

    const float4 a  = ls8[2 * gid + 0];
    const float4 c  = ls8[2 * gid + 1];
    const float4 r  = recS[gid];
    const float p1x = a.x, p1y = a.y, p1z = a.z;
    const float dx = a.w - p1x, dy = c.x - p1y, dz = c.y - p1z;
    const float ttof = c.z;
    const int   orig = __float_as_int(c.w);
    const float tmin = r.x, span = r.y, L = r.z;
    const int   pk   = __float_as_int(r.w);
    const int   jlo  = pk >> 16;
    const int   jhi  = (int)(short)(pk & 0xFFFF);

    // Affine constants (bound proven R10): Q=C0+al*C1 ~ ((p1+t*d)+200)*0.32
    const float sd  = span * 0.0078125f;
    const float C1x = (sd * dx) * 0.32f;
    const float C1y = (sd * dy) * 0.32f;
    const float C1z = (sd * dz) * 0.32f;
    const float C0x = ((p1x + (tmin * dx)) + 200.0f) * 0.32f;
    const float C0y = ((p1y + (tmin * dy)) + 200.0f) * 0.32f;
    const float C0z = ((p1z + (tmin * dz)) + 200.0f) * 0.32f;
    const float D1  = sd * L;
    const float D0  = ((tmin - 0.5f) * L) - ttof;

    float acc0 = 0.0f, acc1 = 0.0f;

    auto sample = [&](float al, float& acc) {
        const float Qx = fmaf(al, C1x, C0x);
        const float Qy = fmaf(al, C1y, C0y);
        const float Qz = fmaf(al, C1z, C0z);
        float fx = floorf(Qx), fy = floorf(Qy), fz = floorf(Qz);
        const float rx = Qx - fx, ry = Qy - fy, rz = Qz - fz;
        const float rmn = fminf(fminf(rx, ry), rz);    // v_min3
        const float rmx = fmaxf(fmaxf(rx, ry), rz);    // v_max3
        if (__builtin_expect(rmn < 1e-3f || rmx > 0.999f, 0)) {
            // EXACT reference chain (unfused, exact-rn, plain '/'):
            const float fr = al * 0.0078125f;
            const float t  = tmin + (fr * span);
            const float ex = p1x + (t * dx);
            const float ey = p1y + (t * dy);
            const float ez = p1z + (t * dz);
            fx = floorf((ex + 200.0f) / 3.125f);
            fy = floorf((ey + 200.0f) / 3.125f);
            fz = floorf((ez + 200.0f) / 3.125f);
        }
        const int vx = (int)fminf(fmaxf(fx, 0.0f), 127.0f);
        const int vy = (int)fminf(fmaxf(fy, 0.0f), 127.0f);
        const int vz = (int)fminf(fmaxf(fz, 0.0f), 127.0f);

        int vidx;
        if (BRICK) {
            vidx = ((((((vx >> 1) << 6) | (vy >> 1)) << 5) | (vz >> 2)) << 4)
                   | ((vx & 1) << 3) | ((vy & 1) << 2) | (vz & 3);
        } else {
            vidx = (((vx << 7) | vy) << 7) | vz;
        }
        const float val = img[vidx];

        const float dev = fmaf(al, D1, D0);
        const float w = (fabsf(dev) <= 90.0f)
            ? 0.06649038f * __expf((dev * dev) * (-5.5555556e-4f)) : 0.0f;
        acc = fmaf(val, w, acc);
    };

    float al = (float)(jlo + s) + 0.5f;
    int j = jlo + s;
    for (; j + SPL <= jhi; j += 2 * SPL) {
        sample(al, acc0);
        sample(al + 8.0f, acc1);
        al += 16.0f;
    }
    if (j <= jhi) sample(al, acc0);

    float acc = acc0 + acc1;

    acc += __shfl_xor(acc, 1, 64);
    acc += __shfl_xor(acc, 2, 64);
    acc += __shfl_xor(acc, 4, 64);

    if (s == 0) {
        const float step = (span * L) * 0.0078125f;
        out[orig] = acc * step;
    }
}

// Fallback (ws too small): self-contained thread-per-LOR, unsorted.
__global__ __launch_bounds__(256) void proj_fallback(
    const float* __restrict__ image,
    const float* __restrict__ lors,
    float* __restrict__ out, int n_lors)
{
#pragma clang fp contract(off)
    const int lor = blockIdx.x * 256 + threadIdx.x;
    if (lor >= n_lors) return;
    const float* lp = lors + (size_t)lor * 7;
    const float p1x = lp[0], p1y = lp[1], p1z = lp[2];
    const float dx = lp[3] - p1x, dy = lp[4] - p1y, dz = lp[5] - p1z;
    const float ttof = lp[6];
    const float L = sqrtf(((dx * dx) + (dy * dy)) + (dz * dz));
    float tmin, tmax;
    slab_clip(p1x, p1y, p1z, dx, dy, dz, tmin, tmax);
    const float span = fmaxf(tmax - tmin, 0.0f);
    if (!(tmax > tmin)) { out[lor] = 0.0f; return; }
    float acc = 0.0f;
    for (int j = 0; j < 128; ++j) {
        const float frac = ((float)j + 0.5f) * 0.0078125f;
        const float t = tmin + (frac * span);
        const float dev = ((t - 0.5f) * L) - ttof;
        if (fabsf(dev) <= 90.0f) {
            const float px = p1x + (t * dx);
            const float py = p1y + (t * dy);
            const float pz = p1z + (t * dz);
            const int vx = vox_of(px + 200.0f);
            const int vy = vox_of(py + 200.0f);
            const int vz = vox_of(pz + 200.0f);
            const float val = image[(((vx << 7) | vy) << 7) | vz];
            const float w = 0.06649038f *
                            __expf((dev * dev) * (-5.5555556e-4f));
            acc += val * w;
        }
    }
    out[lor] = acc * ((span * L) * 0.0078125f);
}

extern "C" void kernel_launch(void* const* d_in, const int* in_sizes, int n_in,
                              void* d_out, int out_size, void* d_ws, size_t ws_size,
                              hipStream_t stream) {
    const float* image = (const float*)d_in[0];   // 128^3 fp32
    const float* lors  = (const float*)d_in[1];   // N x 7 fp32
    float* out = (float*)d_out;                   // N fp32
    const int n = in_sizes[1] / 7;

    // ws layout: counts[NBUCK] | offsets[NBUCK] | bsum[128] | bpre[128] |
    //            tmp[n] | (16B align) recS[n] | ls8[2n] | (256B) bimg[128^3]
    char* base = (char*)d_ws;
    int* counts  = (int*)base;
    int* offsets = counts + NBUCK;
    int* bsum    = offsets + NBUCK;
    int* bpre    = bsum + NSB;
    int* tmp     = bpre + NSB;
    size_t off = (size_t)(2 * NBUCK + 2 * NSB + n) * sizeof(int);
    off = (off + 15) & ~(size_t)15;
    float4* recS = (float4*)(base + off);
    float4* ls8  = (float4*)(base + off + (size_t)n * 16);
    const size_t need = off + (size_t)n * 48;
    size_t bimg_off = (need + 255) & ~(size_t)255;
    const size_t IMG_BYTES = (size_t)128 * 128 * 128 * 4;
    const size_t need_brick = bimg_off + IMG_BYTES;
    float* bimg = (float*)(base + bimg_off);

    const bool do_sort  = (ws_size >= need);
    const bool do_brick = (ws_size >= need_brick);
    const int  nb = (n + 255) / 256;

    // Cooperative-launch capability (cached host-side queries; capture-safe).
    static int coop_max_blocks = -2;   // -2 = unqueried
    if (coop_max_blocks == -2) {
        int dev = 0; hipGetDevice(&dev);
        int sup = 0;
        hipDeviceGetAttribute(&sup, hipDeviceAttributeCooperativeLaunch, dev);
        if (!sup) {
            coop_max_blocks = -1;
        } else {
            hipDeviceProp_t prop;
            if (hipGetDeviceProperties(&prop, dev) != hipSuccess) {
                coop_max_blocks = -1;
            } else {
                int occ = 0;
                if (hipOccupancyMaxActiveBlocksPerMultiprocessor(
                        &occ, setup_kernel, 256, 0) != hipSuccess || occ < 1) {
                    coop_max_blocks = -1;
                } else {
                    coop_max_blocks = occ * prop.multiProcessorCount;
                }
            }
        }
    }
    const bool try_coop = do_sort && do_brick && (nb > NSB + 32) &&
                          (coop_max_blocks >= nb);

    if (!do_sort) {
        proj_fallback<<<nb, 256, 0, stream>>>(image, lors, out, n);
        return;
    }

    hipMemsetAsync(counts, 0, NBUCK * sizeof(int), stream);

    bool coop_done = false;
    if (try_coop) {
        void* args[] = {(void*)&lors, (void*)&image, (void*)&counts,
                        (void*)&offsets, (void*)&bsum, (void*)&bpre,
                        (void*)&recS, (void*)&ls8, (void*)&bimg, (void*)&n};
        hipError_t e = hipLaunchCooperativeKernel(
            (const void*)setup_kernel, dim3(nb), dim3(256), args, 0, stream);
        coop_done = (e == hipSuccess);
    }

    if (!coop_done) {
        bucket_kernel<<<nb, 256, 0, stream>>>(lors, counts, tmp, n);
        scan_kernel<<<1, 1024, 0, stream>>>(counts, offsets);
        scatter_kernel<<<nb, 256, 0, stream>>>(lors, tmp, offsets, recS, ls8, n);
        if (do_brick)
            brickify_kernel<<<(128 * 128 * 128) / 256, 256, 0, stream>>>(image,
                                                                         bimg);
    }

    const int nthreads = n * SPL;
    const int nblocks = (nthreads + 255) / 256;
    const int nb8 = ((nblocks + 7) / 8) * 8;
    if (do_brick || coop_done) {
        proj_kernel<true><<<nb8, 256, 0, stream>>>(bimg, recS, ls8, out, n,
                                                   nb8 >> 3);
    } else {
        proj_kernel<false><<<nb8, 256, 0, stream>>>(image, recS, ls8, out, n,
                                                    nb8 >> 3);
    }
}

// Round 6
// 133.879 us; speedup vs baseline: 3.1961x; 3.1961x over previous
//
#include <hip/hip_runtime.h>
#include <math.h>

// TOF PET forward projection.
// History: R3 97us proj (L2 thrash) -> R4 Morton sort FETCH 215->26MB ->
// R6 4 lanes/LOR: proj 67 -> R7 sorted records + 8 lanes: proj 50 -> R8
// exact-fast-path voxel divide: 44.5 (VALU 74->54) -> R9 unroll: NEUTRAL ->
// R10 affine index: NEUTRAL -> R11 2x2x4 brick gather: proj ~42-44, total
// 138.5 -> R12 cooperative fused setup: FAILED (grid.sync x4 over 782
// blocks = 325us kernel; coop grid barriers are ~100x a dispatch gap —
// NEVER fuse via grid.sync here). Reverted to R11.
// R13: sync-free half of the R12 idea: scan (1 block, 255 CUs idle ~8us)
// and brickify (independent 2M threads) fused into ONE dispatch — block 0
// scans, blocks 1..2048 brickify. No grid.sync; scatter/proj launch after
// it completes, same dependency order, one less dispatch + brickify hidden.
// Budget @138.5: fill 44 (harness, fixed) | proj ~43 | setup ~51.
// Index-path math STRICTLY UNFUSED exact-rn f32 — DO NOT approximate or
// contract (R0-R2: voxel flips => absmax 0.14 > 0.071). Affine guard bound
// proven R10 (fallback to exact chain within 1e-3 of integer boundary).
// Summation order free (validated R4/R5/R6).

#define NB_POS 4096          // 16^3 Morton cells, 25 mm
#define NCLS   8             // window-length classes (16-sample bins)
#define NBUCK  (NB_POS * NCLS)
#define SPL    8             // lanes per LOR

__device__ __forceinline__ int morton4(int x, int y, int z) {
    int m = 0;
#pragma unroll
    for (int b = 0; b < 4; ++b) {
        m |= ((x >> b) & 1) << (3 * b + 0);
        m |= ((y >> b) & 1) << (3 * b + 1);
        m |= ((z >> b) & 1) << (3 * b + 2);
    }
    return m;
}

// Fallback-kernel voxel index: bit-identical to (int)floorf(xs/3.125f).
__device__ __forceinline__ int vox_of(float xs) {
#pragma clang fp contract(off)
    float q  = xs * 0.32f;
    float fq = floorf(q);
    float f  = q - fq;                      // exact (Sterbenz-range)
    if (__builtin_expect(f < 1e-4f || f > 0.9999f, 0)) {
        fq = floorf(xs / 3.125f);           // exact rn div — rare path
    }
    return min(max((int)fq, 0), 127);
}

// Slab clip (strictly unfused, exact rn divs — reference-visible tmin/span).
__device__ __forceinline__ void slab_clip(
    float p1x, float p1y, float p1z, float dx, float dy, float dz,
    float& tmin, float& tmax)
{
    const float eps = 1e-8f;
    float sdx = (fabsf(dx) < eps) ? eps : dx;
    float sdy = (fabsf(dy) < eps) ? eps : dy;
    float sdz = (fabsf(dz) < eps) ? eps : dz;
    float tax = (-200.f - p1x) / sdx, tbx = (200.f - p1x) / sdx;
    float tay = (-200.f - p1y) / sdy, tby = (200.f - p1y) / sdy;
    float taz = (-200.f - p1z) / sdz, tbz = (200.f - p1z) / sdz;
    tmin = fmaxf(fmaxf(fmaxf(fminf(tax, tbx), fminf(tay, tby)),
                       fminf(taz, tbz)), 0.f);
    tmax = fminf(fminf(fminf(fmaxf(tax, tbx), fmaxf(tay, tby)),
                       fmaxf(taz, tbz)), 1.f);
}

__global__ void bucket_kernel(const float* __restrict__ lors,
                              int* __restrict__ counts,
                              int* __restrict__ tmp, int n) {
#pragma clang fp contract(off)
    int i = blockIdx.x * 256 + threadIdx.x;
    if (i >= n) return;
    const float* lp = lors + (size_t)i * 7;
    float p1x = lp[0], p1y = lp[1], p1z = lp[2];
    float dx = lp[3] - p1x, dy = lp[4] - p1y, dz = lp[5] - p1z;
    float tt = lp[6];
    float L = sqrtf(((dx * dx) + (dy * dy)) + (dz * dz));

    float tmin, tmax;
    slab_clip(p1x, p1y, p1z, dx, dy, dz, tmin, tmax);

    unsigned key;
    if (!(tmax > tmin) || !(L > 0.f)) {
        // Invalids: spread uniformly (kills R5's one-bucket atomic storm).
        key = (unsigned)i & (NBUCK - 1);
    } else {
        float span = tmax - tmin;
        // TOF-center cell (sort key only; approx math OK here)
        float tc = fminf(fmaxf(0.5f + tt / L, tmin), tmax);
        float px = p1x + tc * dx, py = p1y + tc * dy, pz = p1z + tc * dz;
        int cx = (int)fminf(fmaxf((px + 200.f) * 0.04f, 0.f), 15.f);
        int cy = (int)fminf(fmaxf((py + 200.f) * 0.04f, 0.f), 15.f);
        int cz = (int)fminf(fmaxf((pz + 200.f) * 0.04f, 0.f), 15.f);
        // window length -> 3-bit class (16-sample bins): wave-uniform trips
        float jl = ((0.5f + (tt - 90.f) / L) - tmin) / span * 128.f;
        float jh = ((0.5f + (tt + 90.f) / L) - tmin) / span * 128.f;
        jl = fmaxf(jl, 0.f); jh = fminf(jh, 128.f);
        float wlen = fmaxf(jh - jl, 0.f);
        int cls = min(NCLS - 1, (int)(wlen * (1.f / 16.f)));
        key = ((unsigned)morton4(cx, cy, cz) << 3) | (unsigned)cls;
    }
    atomicAdd(&counts[key], 1);
    tmp[i] = (int)key;
}

// Fused: block 0 = 1024-thread scan of NBUCK counts -> exclusive offsets;
// blocks 1..2048 = brickify (2x2x4 bricks, one 64B line each). Independent
// work, no grid sync — consumers (scatter, proj) launch after completion.
__global__ __launch_bounds__(1024) void scan_brick_kernel(
    const int* __restrict__ counts, int* __restrict__ offsets,
    const float* __restrict__ image, float* __restrict__ bimg) {
    if (blockIdx.x == 0) {
        __shared__ int s[1024];
        int t = threadIdx.x;
        const int PER = NBUCK / 1024;
        int base = t * PER;
        int local[PER];
        int sum = 0;
#pragma unroll
        for (int i = 0; i < PER; ++i) {
            local[i] = counts[base + i]; sum += local[i];
        }
        s[t] = sum;
        __syncthreads();
        for (int off = 1; off < 1024; off <<= 1) {
            int v = (t >= off) ? s[t - off] : 0;
            __syncthreads();
            s[t] += v;
            __syncthreads();
        }
        int excl = (t == 0) ? 0 : s[t - 1];
#pragma unroll
        for (int i = 0; i < PER; ++i) {
            offsets[base + i] = excl; excl += local[i];
        }
    } else {
        // brickify: o = output (bricked) index, coalesced writes
        const int o = (int)(blockIdx.x - 1) * 1024 + (int)threadIdx.x;
        const int off = o & 15;
        const int brick = o >> 4;
        const int bz = brick & 31;
        const int t2 = brick >> 5;
        const int by = t2 & 63;
        const int bx = t2 >> 6;
        const int oz = off & 3, oy = (off >> 2) & 1, ox = off >> 3;
        const int vx = (bx << 1) | ox, vy = (by << 1) | oy,
                  vz = (bz << 2) | oz;
        bimg[o] = image[(((vx << 7) | vy) << 7) | vz];
    }
}

// Non-brick fallback scan (plain).
__global__ void scan_kernel(const int* __restrict__ counts,
                            int* __restrict__ offsets) {
    __shared__ int s[1024];
    int t = threadIdx.x;
    const int PER = NBUCK / 1024;
    int base = t * PER;
    int local[PER];
    int sum = 0;
#pragma unroll
    for (int i = 0; i < PER; ++i) { local[i] = counts[base + i]; sum += local[i]; }
    s[t] = sum;
    __syncthreads();
    for (int off = 1; off < 1024; off <<= 1) {
        int v = (t >= off) ? s[t - off] : 0;
        __syncthreads();
        s[t] += v;
        __syncthreads();
    }
    int excl = (t == 0) ? 0 : s[t - 1];
#pragma unroll
    for (int i = 0; i < PER; ++i) { offsets[base + i] = excl; excl += local[i]; }
}

// Scatter + setup: computes per-LOR ray record once, writes SORTED arrays.
__global__ void scatter_kernel(const float* __restrict__ lors,
                               const int* __restrict__ tmp,
                               int* __restrict__ offsets,
                               float4* __restrict__ recS,   // {tmin,span,L,pack}
                               float4* __restrict__ ls8,    // 2 per LOR
                               int n) {
#pragma clang fp contract(off)
    int i = blockIdx.x * 256 + threadIdx.x;
    if (i >= n) return;
    const float* lp = lors + (size_t)i * 7;
    float p1x = lp[0], p1y = lp[1], p1z = lp[2];
    float p2x = lp[3], p2y = lp[4], p2z = lp[5];
    float tt = lp[6];
    float dx = p2x - p1x, dy = p2y - p1y, dz = p2z - p1z;
    float L = sqrtf(((dx * dx) + (dy * dy)) + (dz * dz));

    float tmin, tmax;
    slab_clip(p1x, p1y, p1z, dx, dy, dz, tmin, tmax);

    float span, recL;
    int jlo, jhi;
    if (!(tmax > tmin) || !(L > 0.f)) {
        // invalid or degenerate (L==0 => step==0 => out 0 regardless)
        tmin = 0.f; span = 0.f; recL = 0.f; jlo = 0; jhi = -1;
    } else {
        span = tmax - tmin;
        recL = L;
        // Closed-form sample range of TOF window, +-2 slop (validated R4-R6);
        // exact per-sample test retained in proj -> identical sample set.
        const float tlo = 0.5f + (tt - 90.0f) / L;
        const float thi = 0.5f + (tt + 90.0f) / L;
        float jl = ((tlo - tmin) / span) * 128.0f - 0.5f;
        float jh = ((thi - tmin) / span) * 128.0f - 0.5f;
        jl = fminf(fmaxf(jl - 2.0f, 0.0f), 127.0f);
        jh = fminf(fmaxf(jh + 2.0f, -1.0f), 127.0f);
        jlo = (int)jl;
        jhi = (int)ceilf(jh);
        if (jhi > 127) jhi = 127;
    }

    int slot = atomicAdd(&offsets[tmp[i]], 1);
    int pk = (jlo << 16) | (jhi & 0xFFFF);
    recS[slot] = make_float4(tmin, span, recL, __int_as_float(pk));
    ls8[2 * slot + 0] = make_float4(p1x, p1y, p1z, p2x);
    ls8[2 * slot + 1] = make_float4(p2y, p2z, tt, __int_as_float(i));
}

// Standalone brickify (fallback path only).
__global__ __launch_bounds__(256) void brickify_kernel(
    const float* __restrict__ image, float* __restrict__ bimg) {
    const int o = blockIdx.x * 256 + threadIdx.x;
    const int off = o & 15;
    const int brick = o >> 4;
    const int bz = brick & 31;
    const int t  = brick >> 5;
    const int by = t & 63;
    const int bx = t >> 6;
    const int oz = off & 3, oy = (off >> 2) & 1, ox = off >> 3;
    const int vx = (bx << 1) | ox, vy = (by << 1) | oy, vz = (bz << 2) | oz;
    bimg[o] = image[(((vx << 7) | vy) << 7) | vz];
}

template <bool BRICK>
__global__ __launch_bounds__(256) void proj_kernel(
    const float* __restrict__ img,     // bricked if BRICK, else linear
    const float4* __restrict__ recS,
    const float4* __restrict__ ls8,
    float* __restrict__ out,
    int n_lors, int chunks)
{
#pragma clang fp contract(off)
    const int b = blockIdx.x;
    const int sb = (b & 7) * chunks + (b >> 3);    // XCD swizzle
    const int idx = sb * 256 + (int)threadIdx.x;
    const int gid = idx >> 3;          // sorted LOR slot
    const int s   = idx & 7;           // sub-lane 0..7
    if (gid >= n_lors) return;

    const float4 a  = ls8[2 * gid + 0];
    const float4 c  = ls8[2 * gid + 1];
    const float4 r  = recS[gid];
    const float p1x = a.x, p1y = a.y, p1z = a.z;
    const float dx = a.w - p1x, dy = c.x - p1y, dz = c.y - p1z;
    const float ttof = c.z;
    const int   orig = __float_as_int(c.w);
    const float tmin = r.x, span = r.y, L = r.z;
    const int   pk   = __float_as_int(r.w);
    const int   jlo  = pk >> 16;
    const int   jhi  = (int)(short)(pk & 0xFFFF);

    // Affine constants (bound proven R10): Q=C0+al*C1 ~ ((p1+t*d)+200)*0.32
    const float sd  = span * 0.0078125f;
    const float C1x = (sd * dx) * 0.32f;
    const float C1y = (sd * dy) * 0.32f;
    const float C1z = (sd * dz) * 0.32f;
    const float C0x = ((p1x + (tmin * dx)) + 200.0f) * 0.32f;
    const float C0y = ((p1y + (tmin * dy)) + 200.0f) * 0.32f;
    const float C0z = ((p1z + (tmin * dz)) + 200.0f) * 0.32f;
    const float D1  = sd * L;
    const float D0  = ((tmin - 0.5f) * L) - ttof;

    float acc0 = 0.0f, acc1 = 0.0f;

    auto sample = [&](float al, float& acc) {
        const float Qx = fmaf(al, C1x, C0x);
        const float Qy = fmaf(al, C1y, C0y);
        const float Qz = fmaf(al, C1z, C0z);
        float fx = floorf(Qx), fy = floorf(Qy), fz = floorf(Qz);
        const float rx = Qx - fx, ry = Qy - fy, rz = Qz - fz;
        const float rmn = fminf(fminf(rx, ry), rz);    // v_min3
        const float rmx = fmaxf(fmaxf(rx, ry), rz);    // v_max3
        if (__builtin_expect(rmn < 1e-3f || rmx > 0.999f, 0)) {
            // EXACT reference chain (unfused, exact-rn, plain '/'):
            const float fr = al * 0.0078125f;
            const float t  = tmin + (fr * span);
            const float ex = p1x + (t * dx);
            const float ey = p1y + (t * dy);
            const float ez = p1z + (t * dz);
            fx = floorf((ex + 200.0f) / 3.125f);
            fy = floorf((ey + 200.0f) / 3.125f);
            fz = floorf((ez + 200.0f) / 3.125f);
        }
        const int vx = (int)fminf(fmaxf(fx, 0.0f), 127.0f);
        const int vy = (int)fminf(fmaxf(fy, 0.0f), 127.0f);
        const int vz = (int)fminf(fmaxf(fz, 0.0f), 127.0f);

        int vidx;
        if (BRICK) {
            vidx = ((((((vx >> 1) << 6) | (vy >> 1)) << 5) | (vz >> 2)) << 4)
                   | ((vx & 1) << 3) | ((vy & 1) << 2) | (vz & 3);
        } else {
            vidx = (((vx << 7) | vy) << 7) | vz;
        }
        const float val = img[vidx];

        const float dev = fmaf(al, D1, D0);
        const float w = (fabsf(dev) <= 90.0f)
            ? 0.06649038f * __expf((dev * dev) * (-5.5555556e-4f)) : 0.0f;
        acc = fmaf(val, w, acc);
    };

    float al = (float)(jlo + s) + 0.5f;
    int j = jlo + s;
    for (; j + SPL <= jhi; j += 2 * SPL) {
        sample(al, acc0);
        sample(al + 8.0f, acc1);
        al += 16.0f;
    }
    if (j <= jhi) sample(al, acc0);

    float acc = acc0 + acc1;

    acc += __shfl_xor(acc, 1, 64);
    acc += __shfl_xor(acc, 2, 64);
    acc += __shfl_xor(acc, 4, 64);

    if (s == 0) {
        const float step = (span * L) * 0.0078125f;
        out[orig] = acc * step;
    }
}

// Fallback (ws too small): self-contained thread-per-LOR, unsorted.
__global__ __launch_bounds__(256) void proj_fallback(
    const float* __restrict__ image,
    const float* __restrict__ lors,
    float* __restrict__ out, int n_lors)
{
#pragma clang fp contract(off)
    const int lor = blockIdx.x * 256 + threadIdx.x;
    if (lor >= n_lors) return;
    const float* lp = lors + (size_t)lor * 7;
    const float p1x = lp[0], p1y = lp[1], p1z = lp[2];
    const float dx = lp[3] - p1x, dy = lp[4] - p1y, dz = lp[5] - p1z;
    const float ttof = lp[6];
    const float L = sqrtf(((dx * dx) + (dy * dy)) + (dz * dz));
    float tmin, tmax;
    slab_clip(p1x, p1y, p1z, dx, dy, dz, tmin, tmax);
    const float span = fmaxf(tmax - tmin, 0.0f);
    if (!(tmax > tmin)) { out[lor] = 0.0f; return; }
    float acc = 0.0f;
    for (int j = 0; j < 128; ++j) {
        const float frac = ((float)j + 0.5f) * 0.0078125f;
        const float t = tmin + (frac * span);
        const float dev = ((t - 0.5f) * L) - ttof;
        if (fabsf(dev) <= 90.0f) {
            const float px = p1x + (t * dx);
            const float py = p1y + (t * dy);
            const float pz = p1z + (t * dz);
            const int vx = vox_of(px + 200.0f);
            const int vy = vox_of(py + 200.0f);
            const int vz = vox_of(pz + 200.0f);
            const float val = image[(((vx << 7) | vy) << 7) | vz];
            const float w = 0.06649038f *
                            __expf((dev * dev) * (-5.5555556e-4f));
            acc += val * w;
        }
    }
    out[lor] = acc * ((span * L) * 0.0078125f);
}

extern "C" void kernel_launch(void* const* d_in, const int* in_sizes, int n_in,
                              void* d_out, int out_size, void* d_ws, size_t ws_size,
                              hipStream_t stream) {
    const float* image = (const float*)d_in[0];   // 128^3 fp32
    const float* lors  = (const float*)d_in[1];   // N x 7 fp32
    float* out = (float*)d_out;                   // N fp32
    const int n = in_sizes[1] / 7;

    // ws layout: counts[NBUCK] | offsets[NBUCK] | tmp[n] | (16B align)
    //            recS[n]x16B | ls8[2n]x16B | (256B align) bimg[128^3]
    char* base = (char*)d_ws;
    int* counts  = (int*)base;
    int* offsets = counts + NBUCK;
    int* tmp     = offsets + NBUCK;
    size_t off = (size_t)(2 * NBUCK + n) * sizeof(int);
    off = (off + 15) & ~(size_t)15;
    float4* recS = (float4*)(base + off);
    float4* ls8  = (float4*)(base + off + (size_t)n * 16);
    const size_t need = off + (size_t)n * 48;
    size_t bimg_off = (need + 255) & ~(size_t)255;
    const size_t IMG_BYTES = (size_t)128 * 128 * 128 * 4;
    const size_t need_brick = bimg_off + IMG_BYTES;
    float* bimg = (float*)(base + bimg_off);

    const bool do_sort  = (ws_size >= need);
    const bool do_brick = (ws_size >= need_brick);
    const int  nb = (n + 255) / 256;

    if (!do_sort) {
        proj_fallback<<<nb, 256, 0, stream>>>(image, lors, out, n);
        return;
    }

    hipMemsetAsync(counts, 0, NBUCK * sizeof(int), stream);
    bucket_kernel<<<nb, 256, 0, stream>>>(lors, counts, tmp, n);
    if (do_brick) {
        // block 0: scan; blocks 1..2048: brickify (128^3 / 1024)
        scan_brick_kernel<<<1 + (128 * 128 * 128) / 1024, 1024, 0, stream>>>(
            counts, offsets, image, bimg);
    } else {
        scan_kernel<<<1, 1024, 0, stream>>>(counts, offsets);
    }
    scatter_kernel<<<nb, 256, 0, stream>>>(lors, tmp, offsets, recS, ls8, n);

    const int nthreads = n * SPL;
    const int nblocks = (nthreads + 255) / 256;
    const int nb8 = ((nblocks + 7) / 8) * 8;
    if (do_brick) {
        proj_kernel<true><<<nb8, 256, 0, stream>>>(bimg, recS, ls8, out, n,
                                                   nb8 >> 3);
    } else {
        proj_kernel<false><<<nb8, 256, 0, stream>>>(image, recS, ls8, out, n,
                                                    nb8 >> 3);
    }
}

// Round 7
// 132.158 us; speedup vs baseline: 3.2377x; 1.0130x over previous
//
#include <hip/hip_runtime.h>
#include <math.h>

// TOF PET forward projection.
// History: R3 97us proj (L2 thrash) -> R4 Morton sort FETCH 215->26MB ->
// R6 4 lanes/LOR: proj 67 -> R7 sorted records + 8 lanes: proj 50 -> R8
// exact-fast-path voxel divide: 44.5 (VALU 74->54) -> R9 unroll: NEUTRAL ->
// R10 affine index: NEUTRAL -> R11 2x2x4 brick gather: proj ~42-44 ->
// R12 cooperative fused setup: FAILED (grid.sync x4 = 325us; NEVER fuse via
// grid.sync here) -> R13 scan+brickify one dispatch: 138.5 -> 133.9 WIN.
// R14: R10's neutrality explained: guard band 1e-3 => per-sample fallback
// 6e-3 => WAVE-level exec-mask cost 1-(1-6e-3)^64 = 32% of iterations ran
// the 80-op exact chain (+26 ops/sample amortized, cancelling the affine
// win). Fix: (a) guard 1e-3 -> 3e-4 (rigorous |Q-ref| bound 1.16e-4, 2.6x
// margin, same bound structure as R8's validated 4.3x) => wave rate 11%;
// (b) fallback divides use the R8-validated *0.32f + 1e-4-guard + nested
// true-divide (bit-identical, 5 rounds validated) => fallback ~80 -> ~30
// ops. Voxel indices stay BIT-IDENTICAL to numpy in all cases.
// Budget @133.9: fill ~45 (harness, fixed) | proj ~43 | setup+gaps ~46.
// Index-path math STRICTLY UNFUSED exact-rn f32 — DO NOT approximate or
// contract (R0-R2: voxel flips => absmax 0.14 > 0.071 threshold).
// Summation order free (validated R4/R5/R6).

#define NB_POS 4096          // 16^3 Morton cells, 25 mm
#define NCLS   8             // window-length classes (16-sample bins)
#define NBUCK  (NB_POS * NCLS)
#define SPL    8             // lanes per LOR

__device__ __forceinline__ int morton4(int x, int y, int z) {
    int m = 0;
#pragma unroll
    for (int b = 0; b < 4; ++b) {
        m |= ((x >> b) & 1) << (3 * b + 0);
        m |= ((y >> b) & 1) << (3 * b + 1);
        m |= ((z >> b) & 1) << (3 * b + 2);
    }
    return m;
}

// floor(rn(xs/3.125)) bit-identically, cheaply (R8-validated):
// q=xs*0.32f agrees with rn(xs/3.125) to <2.3e-5 abs; floor can only differ
// within 1e-4 of an integer boundary -> exact IEEE '/' there (~2e-4/coord).
__device__ __forceinline__ float floor_div3125(float xs) {
#pragma clang fp contract(off)
    float q  = xs * 0.32f;
    float fq = floorf(q);
    float f  = q - fq;                      // exact (Sterbenz-range)
    if (__builtin_expect(f < 1e-4f || f > 0.9999f, 0)) {
        fq = floorf(xs / 3.125f);           // exact rn div — rare path
    }
    return fq;
}

__device__ __forceinline__ int vox_of(float xs) {
    const float fq = floor_div3125(xs);
    return min(max((int)fq, 0), 127);
}

// Slab clip (strictly unfused, exact rn divs — reference-visible tmin/span).
__device__ __forceinline__ void slab_clip(
    float p1x, float p1y, float p1z, float dx, float dy, float dz,
    float& tmin, float& tmax)
{
    const float eps = 1e-8f;
    float sdx = (fabsf(dx) < eps) ? eps : dx;
    float sdy = (fabsf(dy) < eps) ? eps : dy;
    float sdz = (fabsf(dz) < eps) ? eps : dz;
    float tax = (-200.f - p1x) / sdx, tbx = (200.f - p1x) / sdx;
    float tay = (-200.f - p1y) / sdy, tby = (200.f - p1y) / sdy;
    float taz = (-200.f - p1z) / sdz, tbz = (200.f - p1z) / sdz;
    tmin = fmaxf(fmaxf(fmaxf(fminf(tax, tbx), fminf(tay, tby)),
                       fminf(taz, tbz)), 0.f);
    tmax = fminf(fminf(fminf(fmaxf(tax, tbx), fmaxf(tay, tby)),
                       fmaxf(taz, tbz)), 1.f);
}

__global__ void bucket_kernel(const float* __restrict__ lors,
                              int* __restrict__ counts,
                              int* __restrict__ tmp, int n) {
#pragma clang fp contract(off)
    int i = blockIdx.x * 256 + threadIdx.x;
    if (i >= n) return;
    const float* lp = lors + (size_t)i * 7;
    float p1x = lp[0], p1y = lp[1], p1z = lp[2];
    float dx = lp[3] - p1x, dy = lp[4] - p1y, dz = lp[5] - p1z;
    float tt = lp[6];
    float L = sqrtf(((dx * dx) + (dy * dy)) + (dz * dz));

    float tmin, tmax;
    slab_clip(p1x, p1y, p1z, dx, dy, dz, tmin, tmax);

    unsigned key;
    if (!(tmax > tmin) || !(L > 0.f)) {
        // Invalids: spread uniformly (kills R5's one-bucket atomic storm).
        key = (unsigned)i & (NBUCK - 1);
    } else {
        float span = tmax - tmin;
        // TOF-center cell (sort key only; approx math OK here)
        float tc = fminf(fmaxf(0.5f + tt / L, tmin), tmax);
        float px = p1x + tc * dx, py = p1y + tc * dy, pz = p1z + tc * dz;
        int cx = (int)fminf(fmaxf((px + 200.f) * 0.04f, 0.f), 15.f);
        int cy = (int)fminf(fmaxf((py + 200.f) * 0.04f, 0.f), 15.f);
        int cz = (int)fminf(fmaxf((pz + 200.f) * 0.04f, 0.f), 15.f);
        // window length -> 3-bit class (16-sample bins): wave-uniform trips
        float jl = ((0.5f + (tt - 90.f) / L) - tmin) / span * 128.f;
        float jh = ((0.5f + (tt + 90.f) / L) - tmin) / span * 128.f;
        jl = fmaxf(jl, 0.f); jh = fminf(jh, 128.f);
        float wlen = fmaxf(jh - jl, 0.f);
        int cls = min(NCLS - 1, (int)(wlen * (1.f / 16.f)));
        key = ((unsigned)morton4(cx, cy, cz) << 3) | (unsigned)cls;
    }
    atomicAdd(&counts[key], 1);
    tmp[i] = (int)key;
}

// Fused: block 0 = 1024-thread scan of NBUCK counts -> exclusive offsets;
// blocks 1..2048 = brickify (2x2x4 bricks, one 64B line each). Independent
// work, no grid sync — consumers (scatter, proj) launch after completion.
__global__ __launch_bounds__(1024) void scan_brick_kernel(
    const int* __restrict__ counts, int* __restrict__ offsets,
    const float* __restrict__ image, float* __restrict__ bimg) {
    if (blockIdx.x == 0) {
        __shared__ int s[1024];
        int t = threadIdx.x;
        const int PER = NBUCK / 1024;
        int base = t * PER;
        int local[PER];
        int sum = 0;
#pragma unroll
        for (int i = 0; i < PER; ++i) {
            local[i] = counts[base + i]; sum += local[i];
        }
        s[t] = sum;
        __syncthreads();
        for (int off = 1; off < 1024; off <<= 1) {
            int v = (t >= off) ? s[t - off] : 0;
            __syncthreads();
            s[t] += v;
            __syncthreads();
        }
        int excl = (t == 0) ? 0 : s[t - 1];
#pragma unroll
        for (int i = 0; i < PER; ++i) {
            offsets[base + i] = excl; excl += local[i];
        }
    } else {
        // brickify: o = output (bricked) index, coalesced writes
        const int o = (int)(blockIdx.x - 1) * 1024 + (int)threadIdx.x;
        const int off = o & 15;
        const int brick = o >> 4;
        const int bz = brick & 31;
        const int t2 = brick >> 5;
        const int by = t2 & 63;
        const int bx = t2 >> 6;
        const int oz = off & 3, oy = (off >> 2) & 1, ox = off >> 3;
        const int vx = (bx << 1) | ox, vy = (by << 1) | oy,
                  vz = (bz << 2) | oz;
        bimg[o] = image[(((vx << 7) | vy) << 7) | vz];
    }
}

// Non-brick fallback scan (plain).
__global__ void scan_kernel(const int* __restrict__ counts,
                            int* __restrict__ offsets) {
    __shared__ int s[1024];
    int t = threadIdx.x;
    const int PER = NBUCK / 1024;
    int base = t * PER;
    int local[PER];
    int sum = 0;
#pragma unroll
    for (int i = 0; i < PER; ++i) { local[i] = counts[base + i]; sum += local[i]; }
    s[t] = sum;
    __syncthreads();
    for (int off = 1; off < 1024; off <<= 1) {
        int v = (t >= off) ? s[t - off] : 0;
        __syncthreads();
        s[t] += v;
        __syncthreads();
    }
    int excl = (t == 0) ? 0 : s[t - 1];
#pragma unroll
    for (int i = 0; i < PER; ++i) { offsets[base + i] = excl; excl += local[i]; }
}

// Scatter + setup: computes per-LOR ray record once, writes SORTED arrays.
__global__ void scatter_kernel(const float* __restrict__ lors,
                               const int* __restrict__ tmp,
                               int* __restrict__ offsets,
                               float4* __restrict__ recS,   // {tmin,span,L,pack}
                               float4* __restrict__ ls8,    // 2 per LOR
                               int n) {
#pragma clang fp contract(off)
    int i = blockIdx.x * 256 + threadIdx.x;
    if (i >= n) return;
    const float* lp = lors + (size_t)i * 7;
    float p1x = lp[0], p1y = lp[1], p1z = lp[2];
    float p2x = lp[3], p2y = lp[4], p2z = lp[5];
    float tt = lp[6];
    float dx = p2x - p1x, dy = p2y - p1y, dz = p2z - p1z;
    float L = sqrtf(((dx * dx) + (dy * dy)) + (dz * dz));

    float tmin, tmax;
    slab_clip(p1x, p1y, p1z, dx, dy, dz, tmin, tmax);

    float span, recL;
    int jlo, jhi;
    if (!(tmax > tmin) || !(L > 0.f)) {
        // invalid or degenerate (L==0 => step==0 => out 0 regardless)
        tmin = 0.f; span = 0.f; recL = 0.f; jlo = 0; jhi = -1;
    } else {
        span = tmax - tmin;
        recL = L;
        // Closed-form sample range of TOF window, +-2 slop (validated R4-R6);
        // exact per-sample test retained in proj -> identical sample set.
        const float tlo = 0.5f + (tt - 90.0f) / L;
        const float thi = 0.5f + (tt + 90.0f) / L;
        float jl = ((tlo - tmin) / span) * 128.0f - 0.5f;
        float jh = ((thi - tmin) / span) * 128.0f - 0.5f;
        jl = fminf(fmaxf(jl - 2.0f, 0.0f), 127.0f);
        jh = fminf(fmaxf(jh + 2.0f, -1.0f), 127.0f);
        jlo = (int)jl;
        jhi = (int)ceilf(jh);
        if (jhi > 127) jhi = 127;
    }

    int slot = atomicAdd(&offsets[tmp[i]], 1);
    int pk = (jlo << 16) | (jhi & 0xFFFF);
    recS[slot] = make_float4(tmin, span, recL, __int_as_float(pk));
    ls8[2 * slot + 0] = make_float4(p1x, p1y, p1z, p2x);
    ls8[2 * slot + 1] = make_float4(p2y, p2z, tt, __int_as_float(i));
}

// Standalone brickify (fallback path only).
__global__ __launch_bounds__(256) void brickify_kernel(
    const float* __restrict__ image, float* __restrict__ bimg) {
    const int o = blockIdx.x * 256 + threadIdx.x;
    const int off = o & 15;
    const int brick = o >> 4;
    const int bz = brick & 31;
    const int t  = brick >> 5;
    const int by = t & 63;
    const int bx = t >> 6;
    const int oz = off & 3, oy = (off >> 2) & 1, ox = off >> 3;
    const int vx = (bx << 1) | ox, vy = (by << 1) | oy, vz = (bz << 2) | oz;
    bimg[o] = image[(((vx << 7) | vy) << 7) | vz];
}

template <bool BRICK>
__global__ __launch_bounds__(256) void proj_kernel(
    const float* __restrict__ img,     // bricked if BRICK, else linear
    const float4* __restrict__ recS,
    const float4* __restrict__ ls8,
    float* __restrict__ out,
    int n_lors, int chunks)
{
#pragma clang fp contract(off)
    const int b = blockIdx.x;
    const int sb = (b & 7) * chunks + (b >> 3);    // XCD swizzle
    const int idx = sb * 256 + (int)threadIdx.x;
    const int gid = idx >> 3;          // sorted LOR slot
    const int s   = idx & 7;           // sub-lane 0..7
    if (gid >= n_lors) return;

    const float4 a  = ls8[2 * gid + 0];
    const float4 c  = ls8[2 * gid + 1];
    const float4 r  = recS[gid];
    const float p1x = a.x, p1y = a.y, p1z = a.z;
    const float dx = a.w - p1x, dy = c.x - p1y, dz = c.y - p1z;
    const float ttof = c.z;
    const int   orig = __float_as_int(c.w);
    const float tmin = r.x, span = r.y, L = r.z;
    const int   pk   = __float_as_int(r.w);
    const int   jlo  = pk >> 16;
    const int   jhi  = (int)(short)(pk & 0xFFFF);

    // Affine constants: Q = C0 + al*C1 ~ ((p1 + t*d) + 200)*0.32 chain.
    // Rigorous worst-case |Q - ref_chain| <= 1.16e-4 voxel units (R14).
    const float sd  = span * 0.0078125f;            // span/128 (exact scale)
    const float C1x = (sd * dx) * 0.32f;
    const float C1y = (sd * dy) * 0.32f;
    const float C1z = (sd * dz) * 0.32f;
    const float C0x = ((p1x + (tmin * dx)) + 200.0f) * 0.32f;
    const float C0y = ((p1y + (tmin * dy)) + 200.0f) * 0.32f;
    const float C0z = ((p1z + (tmin * dz)) + 200.0f) * 0.32f;
    const float D1  = sd * L;
    const float D0  = ((tmin - 0.5f) * L) - ttof;

    float acc0 = 0.0f, acc1 = 0.0f;

    // Guard 3e-4 (2.6x margin on the 1.16e-4 bound): per-sample fallback
    // prob ~1.8e-3 -> wave-level exec cost ~11% (was 32% at 1e-3 — the
    // factor that made R10 neutral). Fallback recomputes the exact unfused
    // chain with the cheap bit-identical divide (floor_div3125).
    auto sample = [&](float al, float& acc) {
        const float Qx = fmaf(al, C1x, C0x);
        const float Qy = fmaf(al, C1y, C0y);
        const float Qz = fmaf(al, C1z, C0z);
        float fx = floorf(Qx), fy = floorf(Qy), fz = floorf(Qz);
        const float rx = Qx - fx, ry = Qy - fy, rz = Qz - fz;
        const float rmn = fminf(fminf(rx, ry), rz);    // v_min3
        const float rmx = fmaxf(fmaxf(rx, ry), rz);    // v_max3
        if (__builtin_expect(rmn < 3e-4f || rmx > 0.9997f, 0)) {
            // EXACT reference chain (unfused, exact-rn):
            const float fr = al * 0.0078125f;          // ((float)j+0.5f)/128
            const float t  = tmin + (fr * span);
            const float ex = p1x + (t * dx);
            const float ey = p1y + (t * dy);
            const float ez = p1z + (t * dz);
            fx = floor_div3125(ex + 200.0f);           // == floorf(./3.125)
            fy = floor_div3125(ey + 200.0f);
            fz = floor_div3125(ez + 200.0f);
        }
        // clamp in float (v_med3), then convert
        const int vx = (int)fminf(fmaxf(fx, 0.0f), 127.0f);
        const int vy = (int)fminf(fmaxf(fy, 0.0f), 127.0f);
        const int vz = (int)fminf(fmaxf(fz, 0.0f), 127.0f);

        int vidx;
        if (BRICK) {
            vidx = ((((((vx >> 1) << 6) | (vy >> 1)) << 5) | (vz >> 2)) << 4)
                   | ((vx & 1) << 3) | ((vy & 1) << 2) | (vz & 3);
        } else {
            vidx = (((vx << 7) | vy) << 7) | vz;
        }
        const float val = img[vidx];

        const float dev = fmaf(al, D1, D0);            // weight path: approx OK
        const float w = (fabsf(dev) <= 90.0f)
            ? 0.06649038f * __expf((dev * dev) * (-5.5555556e-4f)) : 0.0f;
        acc = fmaf(val, w, acc);
    };

    float al = (float)(jlo + s) + 0.5f;                // exact
    int j = jlo + s;
    for (; j + SPL <= jhi; j += 2 * SPL) {
        sample(al, acc0);
        sample(al + 8.0f, acc1);                       // exact (int+0.5 range)
        al += 16.0f;
    }
    if (j <= jhi) sample(al, acc0);                    // <=1 remainder

    float acc = acc0 + acc1;   // summation order free (validated R4/R5/R6)

    // combine 8 sub-lanes
    acc += __shfl_xor(acc, 1, 64);
    acc += __shfl_xor(acc, 2, 64);
    acc += __shfl_xor(acc, 4, 64);

    if (s == 0) {
        // step = (span*L)/128: *0.0078125f bit-identical
        const float step = (span * L) * 0.0078125f;
        out[orig] = acc * step;
    }
}

// Fallback (ws too small): self-contained thread-per-LOR, unsorted.
__global__ __launch_bounds__(256) void proj_fallback(
    const float* __restrict__ image,
    const float* __restrict__ lors,
    float* __restrict__ out, int n_lors)
{
#pragma clang fp contract(off)
    const int lor = blockIdx.x * 256 + threadIdx.x;
    if (lor >= n_lors) return;
    const float* lp = lors + (size_t)lor * 7;
    const float p1x = lp[0], p1y = lp[1], p1z = lp[2];
    const float dx = lp[3] - p1x, dy = lp[4] - p1y, dz = lp[5] - p1z;
    const float ttof = lp[6];
    const float L = sqrtf(((dx * dx) + (dy * dy)) + (dz * dz));
    float tmin, tmax;
    slab_clip(p1x, p1y, p1z, dx, dy, dz, tmin, tmax);
    const float span = fmaxf(tmax - tmin, 0.0f);
    if (!(tmax > tmin)) { out[lor] = 0.0f; return; }
    float acc = 0.0f;
    for (int j = 0; j < 128; ++j) {
        const float frac = ((float)j + 0.5f) * 0.0078125f;
        const float t = tmin + (frac * span);
        const float dev = ((t - 0.5f) * L) - ttof;
        if (fabsf(dev) <= 90.0f) {
            const float px = p1x + (t * dx);
            const float py = p1y + (t * dy);
            const float pz = p1z + (t * dz);
            const int vx = vox_of(px + 200.0f);
            const int vy = vox_of(py + 200.0f);
            const int vz = vox_of(pz + 200.0f);
            const float val = image[(((vx << 7) | vy) << 7) | vz];
            const float w = 0.06649038f *
                            __expf((dev * dev) * (-5.5555556e-4f));
            acc += val * w;
        }
    }
    out[lor] = acc * ((span * L) * 0.0078125f);
}

extern "C" void kernel_launch(void* const* d_in, const int* in_sizes, int n_in,
                              void* d_out, int out_size, void* d_ws, size_t ws_size,
                              hipStream_t stream) {
    const float* image = (const float*)d_in[0];   // 128^3 fp32
    const float* lors  = (const float*)d_in[1];   // N x 7 fp32
    float* out = (float*)d_out;                   // N fp32
    const int n = in_sizes[1] / 7;

    // ws layout: counts[NBUCK] | offsets[NBUCK] | tmp[n] | (16B align)
    //            recS[n]x16B | ls8[2n]x16B | (256B align) bimg[128^3]
    char* base = (char*)d_ws;
    int* counts  = (int*)base;
    int* offsets = counts + NBUCK;
    int* tmp     = offsets + NBUCK;
    size_t off = (size_t)(2 * NBUCK + n) * sizeof(int);
    off = (off + 15) & ~(size_t)15;
    float4* recS = (float4*)(base + off);
    float4* ls8  = (float4*)(base + off + (size_t)n * 16);
    const size_t need = off + (size_t)n * 48;
    size_t bimg_off = (need + 255) & ~(size_t)255;
    const size_t IMG_BYTES = (size_t)128 * 128 * 128 * 4;
    const size_t need_brick = bimg_off + IMG_BYTES;
    float* bimg = (float*)(base + bimg_off);

    const bool do_sort  = (ws_size >= need);
    const bool do_brick = (ws_size >= need_brick);
    const int  nb = (n + 255) / 256;

    if (!do_sort) {
        proj_fallback<<<nb, 256, 0, stream>>>(image, lors, out, n);
        return;
    }

    hipMemsetAsync(counts, 0, NBUCK * sizeof(int), stream);
    bucket_kernel<<<nb, 256, 0, stream>>>(lors, counts, tmp, n);
    if (do_brick) {
        // block 0: scan; blocks 1..2048: brickify (128^3 / 1024)
        scan_brick_kernel<<<1 + (128 * 128 * 128) / 1024, 1024, 0, stream>>>(
            counts, offsets, image, bimg);
    } else {
        scan_kernel<<<1, 1024, 0, stream>>>(counts, offsets);
    }
    scatter_kernel<<<nb, 256, 0, stream>>>(lors, tmp, offsets, recS, ls8, n);

    const int nthreads = n * SPL;
    const int nblocks = (nthreads + 255) / 256;
    const int nb8 = ((nblocks + 7) / 8) * 8;
    if (do_brick) {
        proj_kernel<true><<<nb8, 256, 0, stream>>>(bimg, recS, ls8, out, n,
                                                   nb8 >> 3);
    } else {
        proj_kernel<false><<<nb8, 256, 0, stream>>>(image, recS, ls8, out, n,
                                                    nb8 >> 3);
    }
}